// Round 5
// baseline (145.691 us; speedup 1.0000x reference)
//
#include <hip/hip_runtime.h>
#include <hip/hip_bf16.h>

#define HW 4096  // 64*64 spatial

// Static device scratch (24 MiB): qkv[m][b][o][h][w] fp32, m in {0:q,1:k,2:v}.
// Fully rewritten by qkv_proj before attn reads it on every launch -> graph-safe.
__device__ float g_qkv[3 * 8 * 64 * HW];

// One block per (b,h). Weights are read at WAVE-UNIFORM addresses (o depends only
// on readfirstlane(t>>6) and unrolled oi) -> compiler lowers them to SMEM s_load,
// so the 3072 FMAs/thread are pure v_fmac with an SGPR operand. x column lives in
// VGPRs after one LDS pass. R4 showed the LDS-broadcast version was LDS-issue
// bound at 44.8 us (VALUBusy 27%); VALU floor is ~5 us.
__global__ __launch_bounds__(256) void qkv_proj(
    const float* __restrict__ x,
    const float* __restrict__ wq,
    const float* __restrict__ wk,
    const float* __restrict__ wv)
{
    __shared__ float xs[64][64];      // [c][w] 16 KB
    const int t = threadIdx.x;
    const int b = blockIdx.x >> 6;
    const int h = blockIdx.x & 63;

    const float* xrow = x + (size_t)b * 64 * HW + (size_t)h * 64;
    for (int i = t; i < 64 * 64; i += 256) {
        int c = i >> 6, w = i & 63;
        xs[c][w] = xrow[(size_t)c * HW + w];
    }
    __syncthreads();

    const int w = t & 63;
    const int ou = __builtin_amdgcn_readfirstlane(t >> 6);  // wave-uniform 0..3

    float xr[64];
    #pragma unroll
    for (int c = 0; c < 64; ++c) xr[c] = xs[c][w];  // lane-stride 4B -> 2-way alias, free

    const float* __restrict__ mats[3] = { wq, wk, wv };
    #pragma unroll
    for (int m = 0; m < 3; ++m) {
        const float* __restrict__ wg = mats[m];
        float* op = g_qkv + ((size_t)m * 8 + b) * (64 * HW) + (size_t)h * 64 + w;
        #pragma unroll
        for (int oi = 0; oi < 16; ++oi) {
            const int o = oi * 4 + ou;                     // wave-uniform
            const float* __restrict__ wrow = wg + (o << 6); // uniform addr -> s_load
            float acc = 0.f;
            #pragma unroll
            for (int c = 0; c < 64; ++c)
                acc = fmaf(wrow[c], xr[c], acc);
            op[(size_t)o * HW] = acc;
        }
    }
}

// One block per (b,o): 7x7 local attention over a 64x64 image, k/v halo in LDS.
// rel_w/rel_h are dead: constant along the 49-entry softmax axis -> cancel
// (softmax shift-invariance). Zero padding + 1x1 conv => k=v=0 outside; those
// entries' logit is q*0=0 and still participates in the softmax.
// k,v interleaved as float2 -> each window tap is one aligned ds_read_b64.
// 8 vertically adjacent pixels per pass share a 14-row window union:
// 196 b64 taps/thread vs R4's 560 scalar b32.
__global__ __launch_bounds__(256) void attn(float* __restrict__ out)
{
    __shared__ float kv[70][72][2];   // 40.3 KB
    const int t = threadIdx.x;
    const int b = blockIdx.x >> 6;
    const int o = blockIdx.x & 63;

    const float* qb = g_qkv + ((size_t)(0 * 8 + b) * 64 + o) * HW;
    const float* kb = g_qkv + ((size_t)(1 * 8 + b) * 64 + o) * HW;
    const float* vb = g_qkv + ((size_t)(2 * 8 + b) * 64 + o) * HW;

    for (int i = t; i < 70 * 70; i += 256) {
        int r = i / 70, c = i - r * 70;
        int gh = r - 3, gw = c - 3;
        float kk = 0.f, vv = 0.f;
        if ((unsigned)gh < 64u && (unsigned)gw < 64u) {
            kk = kb[gh * 64 + gw];
            vv = vb[gh * 64 + gw];
        }
        kv[r][c][0] = kk;   // adjacent -> compiler merges to ds_write_b64
        kv[r][c][1] = vv;
    }
    __syncthreads();

    const int w = t & 63;
    const int band = t >> 6;          // 0..3
    #pragma unroll 1                  // same 8-pixel body both passes (I-cache friendly)
    for (int pass = 0; pass < 2; ++pass) {
        const int hbase = band * 16 + pass * 8;   // 8 vertically adjacent pixels
        float qv[8], den[8], num[8];
        #pragma unroll
        for (int q = 0; q < 8; ++q) {
            qv[q] = qb[(hbase + q) * 64 + w];
            den[q] = 0.f; num[q] = 0.f;
        }
        // halo rows hbase..hbase+13; pixel q uses halo row hbase+rr iff 0<=rr-q<7
        #pragma unroll
        for (int rr = 0; rr < 14; ++rr) {
            #pragma unroll
            for (int dj = 0; dj < 7; ++dj) {
                const float2 kvp = *(const float2*)&kv[hbase + rr][w + dj][0]; // b64, 8B-aligned
                #pragma unroll
                for (int q = 0; q < 8; ++q) {
                    if (rr - q >= 0 && rr - q < 7) {   // compile-time predicate
                        float e = __expf(qv[q] * kvp.x);
                        den[q] += e;
                        num[q] = fmaf(e, kvp.y, num[q]);
                    }
                }
            }
        }
        #pragma unroll
        for (int q = 0; q < 8; ++q)
            out[((size_t)(b * 64 + o)) * HW + (hbase + q) * 64 + w] = num[q] / den[q];
    }
}

extern "C" void kernel_launch(void* const* d_in, const int* in_sizes, int n_in,
                              void* d_out, int out_size, void* d_ws, size_t ws_size,
                              hipStream_t stream)
{
    // d_in: 0=x, 1=wq, 2=wk, 3=wv (fp32), 4=rel_w, 5=rel_h (dead: softmax
    // shift-invariance), 6=kernel_size(7), 7=padding(3) hardcoded.
    qkv_proj<<<dim3(512), dim3(256), 0, stream>>>(
        (const float*)d_in[0], (const float*)d_in[1],
        (const float*)d_in[2], (const float*)d_in[3]);
    attn<<<dim3(512), dim3(256), 0, stream>>>((float*)d_out);
}